// Round 14
// baseline (248.573 us; speedup 1.0000x reference)
//
#include <hip/hip_runtime.h>
#include <hip/hip_bf16.h>

#define DIM 128

typedef __attribute__((ext_vector_type(8))) short bf16x8;
typedef __attribute__((ext_vector_type(4))) float f32x4;

// ---- ws layout (float offsets) ----
#define WS_B12    0        // 128
#define WS_C      128      // 128  (unused; layout stability)
#define WS_SUMEE  256      // 128
#define WS_S      384      // 1
#define WS_ZB     416      // 64   Z buckets (atomic, 64-way)
#define WS_GEB    512      // 32*128 ge buckets (atomic, 32-way)
#define WS_WBF    4608     // 32768 bf16: Wcat[n][k]
#define WS_EEP    20992    // 128*2048 sum_eE partials [d*2048 + blk]  (ends 283136)
#define WS_SEP    283136   // 2048 S partials
#define WS_SP     285184   // N
#define WS_E      547328   // N
#define WS_WEXP   809472   // N

__device__ __forceinline__ unsigned short f2bf(float f) {
    union { float f; unsigned u; } v; v.f = f;
    unsigned r = v.u + 0x7fffu + ((v.u >> 16) & 1u);
    return (unsigned short)(r >> 16);
}

__device__ __forceinline__ float bfbits(unsigned u) {
    union { unsigned u; float f; } v; v.u = u;
    return v.f;
}

// pack two f32 -> one u32 of 2x bf16 (RNE). Compiler emits v_cvt_pk_bf16_f32.
__device__ __forceinline__ unsigned pkbf(float a, float b) {
    union { __hip_bfloat162 h; unsigned u; } cv;
    cv.h = __float22bfloat162_rn(make_float2(a, b));
    return cv.u;
}

// ---------------- K2: one pass over E -> sp, e, per-block {S, sum_eE} partials ----------------
// r14: 2048 blocks x 128 rows (was 1024 x 256). k2 was latency-bound at 4 blocks/CU
// (16 waves/CU): dependent chain load->shfl-reduce->expf->acc per iter. 8 blocks/CU
// doubles the wave pool (32/CU, HW max) to hide it.
__global__ __launch_bounds__(256) void k2_stats(const float* __restrict__ E,
                                                const float* __restrict__ v,
                                                const float* __restrict__ wpa,
                                                const float* __restrict__ bpa,
                                                const float* __restrict__ Wc1,
                                                const float* __restrict__ Wc2,
                                                const float* __restrict__ bc1,
                                                const float* __restrict__ bc2,
                                                float* __restrict__ ws) {
    __shared__ float red[16][128];
    __shared__ float redS[16];
    int t = threadIdx.x;

    // ---- folded k1: weight conversion + bucket zero-init (blocks 0..127 / 0..15 / 0)
    int gid = blockIdx.x * 256 + t;
    unsigned short* wbf_w = (unsigned short*)(ws + WS_WBF);
    if (gid < 32768) {
        int n = gid >> 7, k = gid & 127;
        float val = (n < 128) ? Wc1[n * 128 + k] : Wc2[(n - 128) * 128 + k];
        wbf_w[gid] = f2bf(val);
    }
    if (gid < 4096) ws[WS_GEB + gid] = 0.f;
    if (gid < 128) ws[WS_B12 + gid] = bc1[gid] + bc2[gid];
    if (gid < 64) ws[WS_ZB + gid] = 0.f;

    int wave = t >> 6, lane = t & 63;
    int cl = lane & 15, rs = lane >> 4;
    int row0 = blockIdx.x * 128;
    const float4* E4 = (const float4*)E;

    float4 va = ((const float4*)v)[cl];
    float4 vb = ((const float4*)v)[16 + cl];
    float4 pa = ((const float4*)wpa)[cl];
    float4 pb = ((const float4*)wpa)[16 + cl];
    float bias = bpa[0];

    float4 acc0 = {0.f, 0.f, 0.f, 0.f}, acc1 = {0.f, 0.f, 0.f, 0.f};
    float se = 0.f;
    float* sp_ws = ws + WS_SP;
    float* e_ws = ws + WS_E;

#pragma unroll
    for (int it = 0; it < 8; ++it) {
        int row = row0 + it * 16 + wave * 4 + rs;
        float4 x0 = E4[row * 32 + cl];
        float4 x1 = E4[row * 32 + 16 + cl];

        float dv = x0.x * va.x + x0.y * va.y + x0.z * va.z + x0.w * va.w
                 + x1.x * vb.x + x1.y * vb.y + x1.z * vb.z + x1.w * vb.w;
        float dp = x0.x * pa.x + x0.y * pa.y + x0.z * pa.z + x0.w * pa.w
                 + x1.x * pb.x + x1.y * pb.y + x1.z * pb.z + x1.w * pb.w;
        for (int off = 1; off < 16; off <<= 1) {
            dv += __shfl_xor(dv, off);
            dp += __shfl_xor(dp, off);
        }
        float e = __expf(dp + bias);
        if (cl == 0) {
            sp_ws[row] = dv;
            e_ws[row] = e;
            se += e;
        }
        acc0.x += e * x0.x; acc0.y += e * x0.y; acc0.z += e * x0.z; acc0.w += e * x0.w;
        acc1.x += e * x1.x; acc1.y += e * x1.y; acc1.z += e * x1.z; acc1.w += e * x1.w;
    }
    int rr = wave * 4 + rs;
    float* dst = red[rr];
    dst[cl * 4 + 0] = acc0.x; dst[cl * 4 + 1] = acc0.y;
    dst[cl * 4 + 2] = acc0.z; dst[cl * 4 + 3] = acc0.w;
    dst[64 + cl * 4 + 0] = acc1.x; dst[64 + cl * 4 + 1] = acc1.y;
    dst[64 + cl * 4 + 2] = acc1.z; dst[64 + cl * 4 + 3] = acc1.w;
    if (cl == 0) redS[rr] = se;
    __syncthreads();
    if (t < 128) {
        float s = 0.f;
#pragma unroll
        for (int r = 0; r < 16; ++r) s += red[r][t];
        ws[WS_EEP + t * 2048 + blockIdx.x] = s;
    }
    if (t == 0) {
        float s = 0.f;
#pragma unroll
        for (int r = 0; r < 16; ++r) s += redS[r];
        ws[WS_SEP + blockIdx.x] = s;
    }
}

// ---------------- K2b: reduce partials -> SUMEE[128], S ----------------
__global__ __launch_bounds__(256) void k2b_reduce(float* __restrict__ ws) {
    __shared__ float r4[4];
    int t = threadIdx.x, blk = blockIdx.x;
    const float* src = (blk < 128) ? (ws + WS_EEP + blk * 2048) : (ws + WS_SEP);
    float s = 0.f;
#pragma unroll
    for (int k = 0; k < 8; ++k) s += src[t + 256 * k];
    for (int off = 1; off < 64; off <<= 1) s += __shfl_xor(s, off);
    if ((t & 63) == 0) r4[t >> 6] = s;
    __syncthreads();
    if (t == 0) {
        float tot = r4[0] + r4[1] + r4[2] + r4[3];
        if (blk < 128) ws[WS_SUMEE + blk] = tot;
        else ws[WS_S] = tot;
    }
}

// ---------------- K4: 4-wave transposed MFMA GEMM, 8 tiles/block, 1 barrier/tile ----------------
// r12 structure unchanged (proven 247.9): reg-staged depth-2 from fp32 E (L3-resident),
// in-register RNE bf16 conversion, per-rt accumulators, triple-buffered Elds.
__global__ __launch_bounds__(256, 2) void k4_main(const float* __restrict__ E,
                                                  const float* __restrict__ wvc,
                                                  const float* __restrict__ bvc_p,
                                                  const float* __restrict__ Wc2,
                                                  float* __restrict__ ws) {
    __shared__ unsigned short Elds[3][64 * 136];   // 3 x 17,408 B
    __shared__ __align__(16) float arena[644];
    float* pim2  = arena;            // [2][64][4]
    float* c_lds = arena + 512;      // [128]
    float* zw    = arena + 640;      // [4]
    float* gep_a = arena;            // [4][128] aliases pim2 (post-loop)

    int t = threadIdx.x;
    int w = t >> 6, lane = t & 63, cl = lane & 15, q = lane >> 4;
    int blk = blockIdx.x;
    int row_base = blk * 512;                    // 8 tiles x 64 rows
    const unsigned short* wbf = (const unsigned short*)(ws + WS_WBF);
    const float* e_ws = ws + WS_E;

    float bvc = bvc_p[0];
    float Sv = ws[WS_S];
    int r0 = w * 16 + q * 4;                     // this lane's 4 rows within a tile
    int sr[4], sc[4];
#pragma unroll
    for (int k = 0; k < 4; ++k) { sr[k] = (t + k * 256) >> 4; sc[k] = (t + k * 256) & 15; }

    // A fragments: wave w owns j-tiles {2w, 2w+1} for BOTH W_c1 and W_c2
    bf16x8 aw[2][2][4];   // [jt][0=W1,1=W2][kt]
#pragma unroll
    for (int jt = 0; jt < 2; ++jt) {
#pragma unroll
        for (int kt = 0; kt < 4; ++kt) {
            int jrow = w * 32 + jt * 16 + cl;
            aw[jt][0][kt] = *(const bf16x8*)(wbf + jrow * 128 + kt * 32 + q * 8);
            aw[jt][1][kt] = *(const bf16x8*)(wbf + (128 + jrow) * 128 + kt * 32 + q * 8);
        }
    }

    // per-lane j-row constants: j = w*32 + jt*16 + q*4 + reg
    float b12r[2][4], wvr[2][4];
#pragma unroll
    for (int jt = 0; jt < 2; ++jt)
#pragma unroll
        for (int reg = 0; reg < 4; ++reg) {
            int jr = w * 32 + jt * 16 + q * 4 + reg;
            b12r[jt][reg] = ws[WS_B12 + jr];
            wvr[jt][reg] = wvc[jr];
        }

    // folded k3: c[j] = Wc2[j,:] . sumEE
    if (t < 128) {
        const float4* row = (const float4*)(Wc2 + t * 128);
        const float4* se4 = (const float4*)(ws + WS_SUMEE);
        float4 s4 = {0.f, 0.f, 0.f, 0.f};
#pragma unroll
        for (int k = 0; k < 32; ++k) {
            float4 a = row[k], b = se4[k];
            s4.x += a.x * b.x; s4.y += a.y * b.y; s4.z += a.z * b.z; s4.w += a.w * b.w;
        }
        c_lds[t] = s4.x + s4.y + s4.z + s4.w;
    }

    // stage tile 0 -> buf 0 (fp32 -> bf16 RNE in-register); issue tile-1 loads
    {
        const float* E0 = E + (size_t)row_base * 128;
#pragma unroll
        for (int k = 0; k < 4; ++k) {
            const float* p = E0 + sr[k] * 128 + sc[k] * 8;
            float4 f0 = *(const float4*)p;
            float4 f1 = *(const float4*)(p + 4);
            uint4 u;
            u.x = pkbf(f0.x, f0.y); u.y = pkbf(f0.z, f0.w);
            u.z = pkbf(f1.x, f1.y); u.w = pkbf(f1.z, f1.w);
            *(uint4*)&Elds[0][sr[k] * 136 + sc[k] * 8] = u;
        }
    }
    float4 sN[8];   // tile-(it+1) staged fp32 (held across barrier in regs)
    {
        const float* E1 = E + (size_t)(row_base + 64) * 128;
#pragma unroll
        for (int k = 0; k < 4; ++k) {
            const float* p = E1 + sr[k] * 128 + sc[k] * 8;
            sN[2 * k]     = *(const float4*)p;
            sN[2 * k + 1] = *(const float4*)(p + 4);
        }
    }
    __syncthreads();   // B_pro: buf0/c_lds visible

    float cjr[2][4];
#pragma unroll
    for (int jt = 0; jt < 2; ++jt)
#pragma unroll
        for (int reg = 0; reg < 4; ++reg)
            cjr[jt][reg] = c_lds[w * 32 + jt * 16 + q * 4 + reg];

    float z_lane = 0.f;
    float acc8[8] = {0.f, 0.f, 0.f, 0.f, 0.f, 0.f, 0.f, 0.f};

    for (int it = 0; it < 8; ++it) {
        int cur = it % 3;
        int pb = it & 1;
        int trow0 = row_base + it * 64;

        // write tile it+1 (regs loaded at it-1 / prologue -> full-iter latency slack)
        if (it < 7) {
            int wr = (it + 1) % 3;
#pragma unroll
            for (int k = 0; k < 4; ++k) {
                uint4 u;
                u.x = pkbf(sN[2 * k].x, sN[2 * k].y);
                u.y = pkbf(sN[2 * k].z, sN[2 * k].w);
                u.z = pkbf(sN[2 * k + 1].x, sN[2 * k + 1].y);
                u.w = pkbf(sN[2 * k + 1].z, sN[2 * k + 1].w);
                *(uint4*)&Elds[wr][sr[k] * 136 + sc[k] * 8] = u;
            }
        }
        // issue loads for tile it+2
        if (it < 6) {
            const float* EsN = E + (size_t)(trow0 + 128) * 128;
#pragma unroll
            for (int k = 0; k < 4; ++k) {
                const float* p = EsN + sr[k] * 128 + sc[k] * 8;
                sN[2 * k]     = *(const float4*)p;
                sN[2 * k + 1] = *(const float4*)(p + 4);
            }
        }
        float4 sp4 = *(const float4*)&ws[WS_SP + trow0 + r0];
        float evr[4];
#pragma unroll
        for (int rt = 0; rt < 4; ++rt) evr[rt] = e_ws[trow0 + rt * 16 + cl];

        // per-rt: ds_read b-frags -> 16 MFMA -> epilogue -> pim write (16 acc regs live)
#pragma unroll
        for (int rt = 0; rt < 4; ++rt) {
            bf16x8 b[4];
#pragma unroll
            for (int kt = 0; kt < 4; ++kt)
                b[kt] = *(const bf16x8*)&Elds[cur][(rt * 16 + cl) * 136 + kt * 32 + q * 8];
            f32x4 a00 = {0.f,0.f,0.f,0.f}, a01 = {0.f,0.f,0.f,0.f};
            f32x4 a10 = {0.f,0.f,0.f,0.f}, a11 = {0.f,0.f,0.f,0.f};
#pragma unroll
            for (int kt = 0; kt < 4; ++kt) {
                a00 = __builtin_amdgcn_mfma_f32_16x16x32_bf16(aw[0][0][kt], b[kt], a00, 0, 0, 0);
                a01 = __builtin_amdgcn_mfma_f32_16x16x32_bf16(aw[0][1][kt], b[kt], a01, 0, 0, 0);
                a10 = __builtin_amdgcn_mfma_f32_16x16x32_bf16(aw[1][0][kt], b[kt], a10, 0, 0, 0);
                a11 = __builtin_amdgcn_mfma_f32_16x16x32_bf16(aw[1][1][kt], b[kt], a11, 0, 0, 0);
            }
            float e_v = evr[rt];
            float di_v = 1.0f / (Sv - e_v);
            float p = 0.f;
#pragma unroll
            for (int reg = 0; reg < 4; ++reg) {       // jt=0 first (order matches r12)
                float h = a00[reg] + b12r[0][reg] + (cjr[0][reg] - e_v * a01[reg]) * di_v;
                p = fmaf(wvr[0][reg], fmaxf(h, 0.f), p);
            }
#pragma unroll
            for (int reg = 0; reg < 4; ++reg) {       // then jt=1
                float h = a10[reg] + b12r[1][reg] + (cjr[1][reg] - e_v * a11[reg]) * di_v;
                p = fmaf(wvr[1][reg], fmaxf(h, 0.f), p);
            }
            p += __shfl_xor(p, 16);
            p += __shfl_xor(p, 32);
            if (lane < 16) pim2[(pb * 64 + rt * 16 + lane) * 4 + w] = p;
        }
        __syncthreads();   // B1: pim[pb] + Elds[(it+1)%3] visible; sole barrier this tile

        // wexp: 4 rows/lane; one float4 per row
        float we[4];
#pragma unroll
        for (int rr = 0; rr < 4; ++rr) {
            float4 P = *(const float4*)&pim2[(pb * 64 + r0 + rr) * 4];
            float pi = (P.x + P.y) + (P.z + P.w);
            float spv = (rr == 0) ? sp4.x : (rr == 1) ? sp4.y : (rr == 2) ? sp4.z : sp4.w;
            we[rr] = __expf(spv + bvc + pi);
            z_lane += we[rr];
        }
        if (cl == 0)
            *(float4*)&ws[WS_WEXP + trow0 + r0] = (float4){we[0], we[1], we[2], we[3]};

#pragma unroll
        for (int rr = 0; rr < 4; ++rr) {
            int r = r0 + rr;
            float wer = we[rr];
            uint4 u = *(const uint4*)&Elds[cur][r * 136 + cl * 8];
            acc8[0] += wer * bfbits(u.x << 16);
            acc8[1] += wer * bfbits(u.x & 0xffff0000u);
            acc8[2] += wer * bfbits(u.y << 16);
            acc8[3] += wer * bfbits(u.y & 0xffff0000u);
            acc8[4] += wer * bfbits(u.z << 16);
            acc8[5] += wer * bfbits(u.z & 0xffff0000u);
            acc8[6] += wer * bfbits(u.w << 16);
            acc8[7] += wer * bfbits(u.w & 0xffff0000u);
        }
        // no trailing barrier: triple-buffered Elds / dbuf pim keep next iter's writes
        // WAR-safe (separated from this iter's reads by the NEXT B1)
    }

    __syncthreads();   // all pim reads done -> arena reusable as gep/zw

    z_lane += __shfl_xor(z_lane, 16);
    z_lane += __shfl_xor(z_lane, 32);
    if (lane == 0) zw[w] = z_lane;

#pragma unroll
    for (int jj = 0; jj < 8; ++jj) {
        acc8[jj] += __shfl_xor(acc8[jj], 16);
        acc8[jj] += __shfl_xor(acc8[jj], 32);
    }
    if (lane < 16) {
        *(float4*)&gep_a[w * 128 + cl * 8] = (float4){acc8[0], acc8[1], acc8[2], acc8[3]};
        *(float4*)&gep_a[w * 128 + cl * 8 + 4] = (float4){acc8[4], acc8[5], acc8[6], acc8[7]};
    }
    __syncthreads();

    if (t < 128) {
        float tot = gep_a[t] + gep_a[128 + t] + gep_a[256 + t] + gep_a[384 + t];
        atomicAdd(&ws[WS_GEB + (blk & 31) * 128 + t], tot);
    }
    if (t == 128) {
        float zs = zw[0] + zw[1] + zw[2] + zw[3];
        atomicAdd(&ws[WS_ZB + (blk & 63)], zs);
    }
}

// ---------------- K5: normalize + write outputs ----------------
__global__ __launch_bounds__(256) void k5_final(const float* __restrict__ ws,
                                                float* __restrict__ out) {
    int t = threadIdx.x, blk = blockIdx.x;
    float z = ws[WS_ZB + (t & 63)];
    for (int off = 1; off < 64; off <<= 1) z += __shfl_xor(z, off);
    float invZ = 1.0f / z;
    if (blk < 1024) {
        int i = blk * 256 + t;
        out[128 + i] = ws[WS_WEXP + i] * invZ;
    } else if (t < 128) {
        float s = 0.f;
#pragma unroll
        for (int b = 0; b < 32; ++b) s += ws[WS_GEB + b * 128 + t];
        out[t] = s * invZ;
    }
}

extern "C" void kernel_launch(void* const* d_in, const int* in_sizes, int n_in,
                              void* d_out, int out_size, void* d_ws, size_t ws_size,
                              hipStream_t stream) {
    const float* E   = (const float*)d_in[0];
    const float* v   = (const float*)d_in[1];
    const float* Wc1 = (const float*)d_in[2];
    const float* bc1 = (const float*)d_in[3];
    const float* Wc2 = (const float*)d_in[4];
    const float* bc2 = (const float*)d_in[5];
    const float* wpa = (const float*)d_in[6];
    const float* bpa = (const float*)d_in[7];
    const float* wvc = (const float*)d_in[8];
    const float* bvc = (const float*)d_in[9];
    float* ws  = (float*)d_ws;
    float* out = (float*)d_out;

    k2_stats<<<2048, 256, 0, stream>>>(E, v, wpa, bpa, Wc1, Wc2, bc1, bc2, ws);
    k2b_reduce<<<129, 256, 0, stream>>>(ws);
    k4_main<<<512, 256, 0, stream>>>(E, wvc, bvc, Wc2, ws);
    k5_final<<<1025, 256, 0, stream>>>(ws, out);
}